// Round 2
// baseline (1995.942 us; speedup 1.0000x reference)
//
#include <hip/hip_runtime.h>

#define NROWS 32768
#define DDIM  512
#define KCENT 8192
#define BM 128
#define BN 128
#define BK 64
#define CTS 32   // centroid tiles per split: (KCENT/BN)/2

// out layout (floats): qout[16777216] loss[16777216] idx[32768] cbv[4194304] counts[8192]
#define O_LOSS 16777216
#define O_IDX  33554432
#define O_CBV  33587200
#define O_CNT  37781504

typedef float f32x4 __attribute__((ext_vector_type(4)));
typedef short bf16x8 __attribute__((ext_vector_type(8)));

__device__ __forceinline__ unsigned int bf16_rne(float x) {
    unsigned int u = __float_as_uint(x);
    return (u + 0x7fffu + ((u >> 16) & 1u)) >> 16;
}
__device__ __forceinline__ float bf16f(unsigned int h) {
    return __uint_as_float(h << 16);
}

// ---- kernel 1: centroid squared norms (fp64 accumulate) + counts=1 ----
__global__ __launch_bounds__(256) void vq_cnorm_kernel(
    const float* __restrict__ CB, float* __restrict__ cnorm, float* __restrict__ counts)
{
    const int wid  = threadIdx.x >> 6;
    const int lane = threadIdx.x & 63;
    const int cid  = blockIdx.x * 4 + wid;
    const float4* p = (const float4*)(CB + (size_t)cid * DDIM + lane * 8);
    float4 a = p[0], b = p[1];
    double s = (double)a.x*a.x + (double)a.y*a.y + (double)a.z*a.z + (double)a.w*a.w
             + (double)b.x*b.x + (double)b.y*b.y + (double)b.z*b.z + (double)b.w*b.w;
    #pragma unroll
    for (int off = 32; off > 0; off >>= 1) s += __shfl_down(s, off);
    if (lane == 0) { cnorm[cid] = (float)s; counts[cid] = 1.0f; }
}

// stage 16 consecutive floats of one row into swizzled hi/lo bf16 LDS tiles
__device__ __forceinline__ void stage16(const float* __restrict__ src,
                                        char* dh, char* dl, int r, int q)
{
    float xs[16];
    *(float4*)&xs[0]  = ((const float4*)src)[0];
    *(float4*)&xs[4]  = ((const float4*)src)[1];
    *(float4*)&xs[8]  = ((const float4*)src)[2];
    *(float4*)&xs[12] = ((const float4*)src)[3];
    unsigned int hs[16], ls[16];
    #pragma unroll
    for (int i = 0; i < 16; ++i) {
        unsigned int h = bf16_rne(xs[i]);
        float lf = xs[i] - bf16f(h);   // exact (Sterbenz)
        hs[i] = h;
        ls[i] = bf16_rne(lf);
    }
    unsigned int wh[8], wl[8];
    #pragma unroll
    for (int i = 0; i < 8; ++i) {
        wh[i] = hs[2*i] | (hs[2*i+1] << 16);
        wl[i] = ls[2*i] | (ls[2*i+1] << 16);
    }
    const int sw = (r & 7) << 4;
    const int o0 = r*128 + ((q*32)      ^ sw);
    const int o1 = r*128 + ((q*32 + 16) ^ sw);
    uint4 H0 = {wh[0],wh[1],wh[2],wh[3]}, H1 = {wh[4],wh[5],wh[6],wh[7]};
    uint4 L0 = {wl[0],wl[1],wl[2],wl[3]}, L1 = {wl[4],wl[5],wl[6],wl[7]};
    *(uint4*)(dh + o0) = H0;  *(uint4*)(dh + o1) = H1;
    *(uint4*)(dl + o0) = L0;  *(uint4*)(dl + o1) = L1;
}

// running top-2 update (candidates arrive in increasing index order)
__device__ __forceinline__ void t2_update(float s, int c,
                                          float& v1, int& i1, float& v2, int& i2)
{
    if (s < v1)       { v2 = v1; i2 = i1; v1 = s; i1 = c; }
    else if (s <= v2) { v2 = s;  i2 = c; }
}

// merge top-2 list (b1,bi1,b2,bi2) into (a1,ai1,a2,ai2); first-occurrence ties
__device__ __forceinline__ void t2_merge(float b1, int bi1, float b2, int bi2,
                                         float& a1, int& ai1, float& a2, int& ai2)
{
    if (b1 < a1 || (b1 == a1 && bi1 < ai1)) {
        float o1 = a1; int oi1 = ai1;
        a1 = b1; ai1 = bi1;
        // new second = best of (old first, b2)   [old second >= old first]
        if (b2 < o1 || (b2 == o1 && bi2 < oi1)) { a2 = b2; ai2 = bi2; }
        else                                    { a2 = o1; ai2 = oi1; }
    } else {
        if (b1 < a2 || (b1 == a2 && bi1 < ai2)) { a2 = b1; ai2 = bi1; }
    }
}

// ---- kernel 2: fused split-bf16 distance GEMM + per-split top-2 ----
__global__ __launch_bounds__(512, 2) void vq_argmin_kernel(
    const float* __restrict__ X, const float* __restrict__ CB,
    const float* __restrict__ cnorm,
    int* __restrict__ pmini4)
{
    __shared__ __align__(16) char xh[BM*BK*2], xl[BM*BK*2];
    __shared__ __align__(16) char chs[BN*BK*2], cls[BN*BK*2];

    const int bid   = blockIdx.x;
    const int rb    = (bid >> 1) * BM;
    const int split = bid & 1;
    const int t     = threadIdx.x;
    const int lane  = t & 63;
    const int wid   = t >> 6;
    const int wr    = wid >> 2;    // 0..1 (64-row group)
    const int wc    = wid & 3;     // 0..3 (32-col group)
    const int l15   = lane & 15;
    const int lg    = lane >> 4;

    const int sr = t >> 2;   // staging row 0..127
    const int sq = t & 3;    // staging 16-float quarter

    float rv1[4][4], rv2[4][4];
    int   ri1[4][4], ri2[4][4];
    #pragma unroll
    for (int m = 0; m < 4; ++m)
        #pragma unroll
        for (int j = 0; j < 4; ++j) {
            rv1[m][j] = 3.4e38f; rv2[m][j] = 3.4e38f;
            ri1[m][j] = 0;       ri2[m][j] = 0;
        }

    for (int ct = split*CTS; ct < split*CTS + CTS; ++ct) {
        f32x4 acc[4][2];
        #pragma unroll
        for (int m = 0; m < 4; ++m)
            #pragma unroll
            for (int n = 0; n < 2; ++n) {
                f32x4 z = {0.f, 0.f, 0.f, 0.f};
                acc[m][n] = z;
            }

        for (int dk = 0; dk < DDIM/BK; ++dk) {
            __syncthreads();
            stage16(X  + (size_t)(rb + sr)*DDIM     + dk*BK + sq*16, xh,  xl,  sr, sq);
            stage16(CB + (size_t)(ct*BN + sr)*DDIM  + dk*BK + sq*16, chs, cls, sr, sq);
            __syncthreads();
            #pragma unroll
            for (int ks = 0; ks < 2; ++ks) {
                bf16x8 Ah[4], Al[4], Bh[2], Bl[2];
                const int kb = ks*64 + lg*16;
                #pragma unroll
                for (int m = 0; m < 4; ++m) {
                    const int row = wr*64 + m*16 + l15;
                    const int off = row*128 + (kb ^ ((row & 7) << 4));
                    Ah[m] = *(const bf16x8*)(xh + off);
                    Al[m] = *(const bf16x8*)(xl + off);
                }
                #pragma unroll
                for (int n = 0; n < 2; ++n) {
                    const int row = wc*32 + n*16 + l15;
                    const int off = row*128 + (kb ^ ((row & 7) << 4));
                    Bh[n] = *(const bf16x8*)(chs + off);
                    Bl[n] = *(const bf16x8*)(cls + off);
                }
                #pragma unroll
                for (int m = 0; m < 4; ++m)
                    #pragma unroll
                    for (int n = 0; n < 2; ++n) {
                        acc[m][n] = __builtin_amdgcn_mfma_f32_16x16x32_bf16(Ah[m], Bh[n], acc[m][n], 0, 0, 0);
                        acc[m][n] = __builtin_amdgcn_mfma_f32_16x16x32_bf16(Ah[m], Bl[n], acc[m][n], 0, 0, 0);
                        acc[m][n] = __builtin_amdgcn_mfma_f32_16x16x32_bf16(Al[m], Bh[n], acc[m][n], 0, 0, 0);
                    }
            }
        }
        // epilogue: score = ||c||^2 - 2*dot ; per-lane running top-2
        #pragma unroll
        for (int n = 0; n < 2; ++n) {
            const int col = ct*BN + wc*32 + n*16 + l15;
            const float cn = cnorm[col];
            #pragma unroll
            for (int m = 0; m < 4; ++m)
                #pragma unroll
                for (int j = 0; j < 4; ++j) {
                    float s = fmaf(-2.0f, acc[m][n][j], cn);
                    t2_update(s, col, rv1[m][j], ri1[m][j], rv2[m][j], ri2[m][j]);
                }
        }
    }

    // cross-lane top-2 merge over the 16 lanes sharing a row (butterfly)
    #pragma unroll
    for (int m = 0; m < 4; ++m)
        #pragma unroll
        for (int j = 0; j < 4; ++j) {
            #pragma unroll
            for (int off = 1; off <= 8; off <<= 1) {
                float b1 = __shfl_xor(rv1[m][j], off);
                float b2 = __shfl_xor(rv2[m][j], off);
                int  bi1 = __shfl_xor(ri1[m][j], off);
                int  bi2 = __shfl_xor(ri2[m][j], off);
                t2_merge(b1, bi1, b2, bi2, rv1[m][j], ri1[m][j], rv2[m][j], ri2[m][j]);
            }
        }

    // cross-WAVE merge (the round-1 race): stash per-(row,wc) top-2 in LDS
    float* redv = (float*)xh;   // [128][4][2] floats (reuse tile LDS, post-barrier)
    int*   redi = (int*)xl;     // [128][4][2] ints
    __syncthreads();
    if (l15 == 0) {
        #pragma unroll
        for (int m = 0; m < 4; ++m)
            #pragma unroll
            for (int j = 0; j < 4; ++j) {
                const int rl = wr*64 + m*16 + lg*4 + j;
                redv[(rl*4 + wc)*2 + 0] = rv1[m][j];
                redv[(rl*4 + wc)*2 + 1] = rv2[m][j];
                redi[(rl*4 + wc)*2 + 0] = ri1[m][j];
                redi[(rl*4 + wc)*2 + 1] = ri2[m][j];
            }
    }
    __syncthreads();
    if (t < BM) {
        float a1 = 3.4e38f, a2 = 3.4e38f;
        int  ai1 = 0x7fffffff, ai2 = 0x7fffffff;
        #pragma unroll
        for (int w = 0; w < 4; ++w) {
            float b1 = redv[(t*4 + w)*2 + 0], b2 = redv[(t*4 + w)*2 + 1];
            int  bi1 = redi[(t*4 + w)*2 + 0], bi2 = redi[(t*4 + w)*2 + 1];
            t2_merge(b1, bi1, b2, bi2, a1, ai1, a2, ai2);
        }
        const int row = rb + t;
        pmini4[row*4 + split*2 + 0] = ai1;
        pmini4[row*4 + split*2 + 1] = ai2;
    }
}

// ---- kernel 3: exact fp64 re-evaluation of the <=4 candidates per row ----
__global__ __launch_bounds__(256) void vq_resolve_kernel(
    const float* __restrict__ X, const float* __restrict__ CB,
    const int* __restrict__ pmini4, int* __restrict__ fidx)
{
    const int w    = threadIdx.x >> 6;
    const int lane = threadIdx.x & 63;
    const int row  = blockIdx.x * 4 + w;
    const float4* xp = (const float4*)(X + (size_t)row * DDIM + lane * 8);
    float4 xa = xp[0], xb = xp[1];
    double bd = 1.0e300;
    int    bi = 0x7fffffff;
    for (int c = 0; c < 4; ++c) {
        const int idx = pmini4[row*4 + c];
        const float4* cp = (const float4*)(CB + (size_t)idx * DDIM + lane * 8);
        float4 ca = cp[0], cb = cp[1];
        double d = 0.0, e;
        e = (double)xa.x - ca.x; d += e*e;
        e = (double)xa.y - ca.y; d += e*e;
        e = (double)xa.z - ca.z; d += e*e;
        e = (double)xa.w - ca.w; d += e*e;
        e = (double)xb.x - cb.x; d += e*e;
        e = (double)xb.y - cb.y; d += e*e;
        e = (double)xb.z - cb.z; d += e*e;
        e = (double)xb.w - cb.w; d += e*e;
        #pragma unroll
        for (int off = 32; off > 0; off >>= 1) d += __shfl_down(d, off);
        // only lane 0 has the full sum; only lane 0's decision is used
        if (d < bd || (d == bd && idx < bi)) { bd = d; bi = idx; }
    }
    if (lane == 0) fidx[row] = bi;
}

// ---- kernel 4: gather codebook row, write outputs ----
__global__ __launch_bounds__(128) void vq_output_kernel(
    const float* __restrict__ X, const float* __restrict__ CB,
    const int* __restrict__ fidx, float* __restrict__ out)
{
    const int n = blockIdx.x;
    const int t = threadIdx.x;
    const int idx = fidx[n];
    if (t == 0) out[O_IDX + n] = (float)idx;

    float4 x = ((const float4*)(X  + (size_t)n   * DDIM))[t];
    float4 q = ((const float4*)(CB + (size_t)idx * DDIM))[t];
    float4 qo, lo;
    float d, s;
    d = q.x - x.x; qo.x = x.x + d; s = d*d; lo.x = s + 0.25f*s;
    d = q.y - x.y; qo.y = x.y + d; s = d*d; lo.y = s + 0.25f*s;
    d = q.z - x.z; qo.z = x.z + d; s = d*d; lo.z = s + 0.25f*s;
    d = q.w - x.w; qo.w = x.w + d; s = d*d; lo.w = s + 0.25f*s;

    ((float4*)out)[(size_t)n*128 + t] = qo;
    ((float4*)(out + O_LOSS))[(size_t)n*128 + t] = lo;
}

extern "C" void kernel_launch(void* const* d_in, const int* in_sizes, int n_in,
                              void* d_out, int out_size, void* d_ws, size_t ws_size,
                              hipStream_t stream)
{
    const float* X  = (const float*)d_in[0];
    const float* CB = (const float*)d_in[1];
    float* out = (float*)d_out;

    float* cnorm  = (float*)d_ws;             // 8192 floats
    int*   pmini4 = (int*)(cnorm + KCENT);    // 4*32768 ints
    int*   fidx   = pmini4 + 4*NROWS;         // 32768 ints

    vq_cnorm_kernel<<<KCENT/4, 256, 0, stream>>>(CB, cnorm, out + O_CNT);
    vq_argmin_kernel<<<(NROWS/BM)*2, 512, 0, stream>>>(X, CB, cnorm, pmini4);
    vq_resolve_kernel<<<NROWS/4, 256, 0, stream>>>(X, CB, pmini4, fidx);
    vq_output_kernel<<<NROWS, 128, 0, stream>>>(X, CB, fidx, out);
    hipMemcpyAsync(out + O_CBV, CB, (size_t)KCENT * DDIM * sizeof(float),
                   hipMemcpyDeviceToDevice, stream);
}

// Round 3
// 1287.035 us; speedup vs baseline: 1.5508x; 1.5508x over previous
//
#include <hip/hip_runtime.h>

#define NROWS 32768
#define DDIM  512
#define KCENT 8192
#define BM 128
#define BN 128
#define CTS 32   // centroid tiles per split: (KCENT/BN)/2

// out layout (floats): qout[16777216] loss[16777216] idx[32768] cbv[4194304] counts[8192]
#define O_LOSS 16777216
#define O_IDX  33554432
#define O_CBV  33587200
#define O_CNT  37781504

typedef float f32x4 __attribute__((ext_vector_type(4)));
typedef _Float16 f16x8 __attribute__((ext_vector_type(8)));

// ---- kernel 0: fp32 -> f16, pre-swizzled 16B units: G[R][dk][u] = src[R][dk*64 + (u^(R&7))*8 ..]
__global__ __launch_bounds__(256) void vq_cvt_kernel(
    const float* __restrict__ src, char* __restrict__ dst)
{
    const int gid = blockIdx.x * 256 + threadIdx.x;   // one 16B unit (8 f16)
    const int R   = gid >> 6;
    const int rem = gid & 63;
    const int dk  = rem >> 3;
    const int u   = rem & 7;
    const float4* p = (const float4*)(src + (size_t)R * DDIM + dk * 64 + ((u ^ (R & 7)) * 8));
    float4 a = p[0], b = p[1];
    f16x8 h;
    h[0] = (_Float16)a.x; h[1] = (_Float16)a.y; h[2] = (_Float16)a.z; h[3] = (_Float16)a.w;
    h[4] = (_Float16)b.x; h[5] = (_Float16)b.y; h[6] = (_Float16)b.z; h[7] = (_Float16)b.w;
    *(f16x8*)(dst + (size_t)gid * 16) = h;
}

// ---- kernel 1: centroid squared norms (fp64 accumulate) + counts=1 ----
__global__ __launch_bounds__(256) void vq_cnorm_kernel(
    const float* __restrict__ CB, float* __restrict__ cnorm, float* __restrict__ counts)
{
    const int wid  = threadIdx.x >> 6;
    const int lane = threadIdx.x & 63;
    const int cid  = blockIdx.x * 4 + wid;
    const float4* p = (const float4*)(CB + (size_t)cid * DDIM + lane * 8);
    float4 a = p[0], b = p[1];
    double s = (double)a.x*a.x + (double)a.y*a.y + (double)a.z*a.z + (double)a.w*a.w
             + (double)b.x*b.x + (double)b.y*b.y + (double)b.z*b.z + (double)b.w*b.w;
    #pragma unroll
    for (int off = 32; off > 0; off >>= 1) s += __shfl_down(s, off);
    if (lane == 0) { cnorm[cid] = (float)s; counts[cid] = 1.0f; }
}

__device__ __forceinline__ void t2_update(float s, int c,
                                          float& v1, int& i1, float& v2, int& i2)
{
    if (s < v1)       { v2 = v1; i2 = i1; v1 = s; i1 = c; }
    else if (s <= v2) { v2 = s;  i2 = c; }
}

__device__ __forceinline__ void t2_merge(float b1, int bi1, float b2, int bi2,
                                         float& a1, int& ai1, float& a2, int& ai2)
{
    if (b1 < a1 || (b1 == a1 && bi1 < ai1)) {
        float o1 = a1; int oi1 = ai1;
        a1 = b1; ai1 = bi1;
        if (b2 < o1 || (b2 == o1 && bi2 < oi1)) { a2 = b2; ai2 = bi2; }
        else                                    { a2 = o1; ai2 = oi1; }
    } else {
        if (b1 < a2 || (b1 == a2 && bi1 < ai2)) { a2 = b1; ai2 = bi1; }
    }
}

__device__ __forceinline__ void gl16(const char* g, const char* l)
{
    __builtin_amdgcn_global_load_lds(
        (const __attribute__((address_space(1))) void*)g,
        (__attribute__((address_space(3))) void*)l, 16, 0, 0);
}

// ---- kernel 2: f16 distance GEMM (global_load_lds, 2-phase dbuf) + per-split top-2 ----
__global__ __launch_bounds__(512, 4) void vq_gemm_kernel(
    const char* __restrict__ XsB, const char* __restrict__ CBsB,
    const float* __restrict__ cnorm, int* __restrict__ pmini4)
{
    __shared__ __align__(16) char lds[2][32768];   // per buf: A 16KB | B 16KB

    // bijective XCD swizzle: XCD 0-3 -> split 0, XCD 4-7 -> split 1
    const int swz   = (blockIdx.x & 7) * 64 + (blockIdx.x >> 3);
    const int split = swz >> 8;
    const int rb    = (swz & 255) * BM;
    const int t     = threadIdx.x;
    const int lane  = t & 63;
    const int wid   = t >> 6;
    const int wr    = wid & 3;     // 4 row-groups of 32
    const int wc    = wid >> 2;    // 2 col-groups of 64
    const int l15   = lane & 15;
    const int lg    = lane >> 4;
    const int base_ct = split * CTS;

    // staging constants: unit g = t + i*512; A: i=0,1 ; B: i=2,3
    size_t asrc[2], bsrc[2];
    const char* ldst[4];
    #pragma unroll
    for (int i = 0; i < 2; ++i) {
        const int g = t + i*512, r = g >> 3, u = g & 7;
        asrc[i] = (size_t)(rb + r) * 1024 + u * 16;
    }
    #pragma unroll
    for (int i = 0; i < 2; ++i) {
        const int g = t + i*512, r = g >> 3, u = g & 7;   // row within B tile
        bsrc[i] = (size_t)r * 1024 + u * 16;
    }
    #pragma unroll
    for (int i = 0; i < 4; ++i) ldst[i] = (const char*)&lds[0][0] + i*8192 + wid*1024;

    f32x4 acc[2][4];
    float rv1[2][4], rv2[2][4];
    int   ri1[2][4], ri2[2][4];
    #pragma unroll
    for (int m = 0; m < 2; ++m)
        #pragma unroll
        for (int n = 0; n < 4; ++n) {
            f32x4 z = {0.f,0.f,0.f,0.f};
            acc[m][n] = z;
            rv1[m][n] = 3.4e38f; rv2[m][n] = 3.4e38f;
            ri1[m][n] = 0x7fffffff; ri2[m][n] = 0x7fffffff;
        }

    int cur = 0;
    // prologue: stage step 0 into buf 0
    {
        const char* Xp = XsB;                                    // dk=0
        const char* Cp = CBsB + (size_t)(base_ct*BN) * 1024;     // ct=base_ct, dk=0
        gl16(Xp + asrc[0], ldst[0]);
        gl16(Xp + asrc[1], ldst[1]);
        gl16(Cp + bsrc[0], ldst[2]);
        gl16(Cp + bsrc[1], ldst[3]);
    }
    __syncthreads();

    for (int ctr = 0; ctr < CTS; ++ctr) {
        for (int dk = 0; dk < 8; ++dk) {
            // stage next step into buf cur^1
            const int s2 = ctr*8 + dk + 1;
            if (s2 < CTS*8) {
                const int ndk = s2 & 7;
                const int nct = base_ct + (s2 >> 3);
                const char* Xp = XsB + ndk*128;
                const char* Cp = CBsB + (size_t)(nct*BN) * 1024 + ndk*128;
                const int bo = (cur^1) * 32768;
                gl16(Xp + asrc[0], ldst[0] + bo);
                gl16(Xp + asrc[1], ldst[1] + bo);
                gl16(Cp + bsrc[0], ldst[2] + bo);
                gl16(Cp + bsrc[1], ldst[3] + bo);
            }
            // compute on buf cur
            const char* bb = &lds[cur][0];
            #pragma unroll
            for (int ks = 0; ks < 2; ++ks) {
                f16x8 A[2], B[4];
                #pragma unroll
                for (int m = 0; m < 2; ++m) {
                    const int row = wr*32 + m*16 + l15;
                    const int off = row*128 + (((ks*4 + lg) ^ (row & 7)) * 16);
                    A[m] = *(const f16x8*)(bb + off);
                }
                #pragma unroll
                for (int n = 0; n < 4; ++n) {
                    const int row = wc*64 + n*16 + l15;
                    const int off = 16384 + row*128 + (((ks*4 + lg) ^ (row & 7)) * 16);
                    B[n] = *(const f16x8*)(bb + off);
                }
                #pragma unroll
                for (int m = 0; m < 2; ++m)
                    #pragma unroll
                    for (int n = 0; n < 4; ++n)
                        acc[m][n] = __builtin_amdgcn_mfma_f32_16x16x32_f16(A[m], B[n], acc[m][n], 0, 0, 0);
            }
            __syncthreads();
            cur ^= 1;
        }
        // per-tile epilogue: score = ||c||^2 - 2*dot ; running top-2
        const int ct = base_ct + ctr;
        #pragma unroll
        for (int n = 0; n < 4; ++n) {
            const int col = ct*BN + wc*64 + n*16 + l15;
            const float cn = cnorm[col];
            #pragma unroll
            for (int m = 0; m < 2; ++m) {
                #pragma unroll
                for (int j = 0; j < 4; ++j) {
                    const float s = fmaf(-2.0f, acc[m][n][j], cn);
                    t2_update(s, col, rv1[m][j], ri1[m][j], rv2[m][j], ri2[m][j]);
                }
                f32x4 z = {0.f,0.f,0.f,0.f};
                acc[m][n] = z;
            }
        }
    }

    // cross-lane top-2 merge over the 16 cols (l15 group)
    #pragma unroll
    for (int m = 0; m < 2; ++m)
        #pragma unroll
        for (int j = 0; j < 4; ++j) {
            #pragma unroll
            for (int off = 1; off <= 8; off <<= 1) {
                float b1 = __shfl_xor(rv1[m][j], off);
                float b2 = __shfl_xor(rv2[m][j], off);
                int  bi1 = __shfl_xor(ri1[m][j], off);
                int  bi2 = __shfl_xor(ri2[m][j], off);
                t2_merge(b1, bi1, b2, bi2, rv1[m][j], ri1[m][j], rv2[m][j], ri2[m][j]);
            }
        }

    // cross-wave merge over the 2 col-groups via LDS
    float* redv = (float*)&lds[0][0];     // [128][2][2]
    int*   redi = (int*)&lds[0][4096];    // [128][2][2]
    __syncthreads();
    if (l15 == 0) {
        #pragma unroll
        for (int m = 0; m < 2; ++m)
            #pragma unroll
            for (int j = 0; j < 4; ++j) {
                const int rl = wr*32 + m*16 + lg*4 + j;
                redv[(rl*2 + wc)*2 + 0] = rv1[m][j];
                redv[(rl*2 + wc)*2 + 1] = rv2[m][j];
                redi[(rl*2 + wc)*2 + 0] = ri1[m][j];
                redi[(rl*2 + wc)*2 + 1] = ri2[m][j];
            }
    }
    __syncthreads();
    if (t < BM) {
        float a1 = 3.4e38f, a2 = 3.4e38f;
        int  ai1 = 0x7fffffff, ai2 = 0x7fffffff;
        #pragma unroll
        for (int w = 0; w < 2; ++w) {
            t2_merge(redv[(t*2 + w)*2 + 0], redi[(t*2 + w)*2 + 0],
                     redv[(t*2 + w)*2 + 1], redi[(t*2 + w)*2 + 1],
                     a1, ai1, a2, ai2);
        }
        const int row = rb + t;
        pmini4[row*4 + split*2 + 0] = ai1;
        pmini4[row*4 + split*2 + 1] = ai2;
    }
}

// ---- kernel 3: exact fp64 re-evaluation of the <=4 candidates per row ----
__global__ __launch_bounds__(256) void vq_resolve_kernel(
    const float* __restrict__ X, const float* __restrict__ CB,
    const int* __restrict__ pmini4, int* __restrict__ fidx)
{
    const int w    = threadIdx.x >> 6;
    const int lane = threadIdx.x & 63;
    const int row  = blockIdx.x * 4 + w;
    const float4* xp = (const float4*)(X + (size_t)row * DDIM + lane * 8);
    float4 xa = xp[0], xb = xp[1];
    double bd = 1.0e300;
    int    bi = 0x7fffffff;
    for (int c = 0; c < 4; ++c) {
        const int idx = pmini4[row*4 + c];
        const float4* cp = (const float4*)(CB + (size_t)idx * DDIM + lane * 8);
        float4 ca = cp[0], cb = cp[1];
        double d = 0.0, e;
        e = (double)xa.x - ca.x; d += e*e;
        e = (double)xa.y - ca.y; d += e*e;
        e = (double)xa.z - ca.z; d += e*e;
        e = (double)xa.w - ca.w; d += e*e;
        e = (double)xb.x - cb.x; d += e*e;
        e = (double)xb.y - cb.y; d += e*e;
        e = (double)xb.z - cb.z; d += e*e;
        e = (double)xb.w - cb.w; d += e*e;
        #pragma unroll
        for (int off = 32; off > 0; off >>= 1) d += __shfl_down(d, off);
        if (d < bd || (d == bd && idx < bi)) { bd = d; bi = idx; }
    }
    if (lane == 0) fidx[row] = bi;
}

// ---- kernel 4: gather codebook row, write outputs ----
__global__ __launch_bounds__(128) void vq_output_kernel(
    const float* __restrict__ X, const float* __restrict__ CB,
    const int* __restrict__ fidx, float* __restrict__ out)
{
    const int n = blockIdx.x;
    const int t = threadIdx.x;
    const int idx = fidx[n];
    if (t == 0) out[O_IDX + n] = (float)idx;

    float4 x = ((const float4*)(X  + (size_t)n   * DDIM))[t];
    float4 q = ((const float4*)(CB + (size_t)idx * DDIM))[t];
    float4 qo, lo;
    float d, s;
    d = q.x - x.x; qo.x = x.x + d; s = d*d; lo.x = s + 0.25f*s;
    d = q.y - x.y; qo.y = x.y + d; s = d*d; lo.y = s + 0.25f*s;
    d = q.z - x.z; qo.z = x.z + d; s = d*d; lo.z = s + 0.25f*s;
    d = q.w - x.w; qo.w = x.w + d; s = d*d; lo.w = s + 0.25f*s;

    ((float4*)out)[(size_t)n*128 + t] = qo;
    ((float4*)(out + O_LOSS))[(size_t)n*128 + t] = lo;
}

extern "C" void kernel_launch(void* const* d_in, const int* in_sizes, int n_in,
                              void* d_out, int out_size, void* d_ws, size_t ws_size,
                              hipStream_t stream)
{
    const float* X  = (const float*)d_in[0];
    const float* CB = (const float*)d_in[1];
    float* out = (float*)d_out;

    // big scratch lives in out regions (fully rewritten by the final kernels)
    char* XsB  = (char*)out;                 // 32 MB pre-swizzled f16 X   (qout region)
    char* CBsB = (char*)(out + O_LOSS);      //  8 MB pre-swizzled f16 CB  (loss region)

    float* cnorm  = (float*)d_ws;            // 8192 floats
    int*   pmini4 = (int*)(cnorm + KCENT);   // 4*32768 ints
    int*   fidx   = pmini4 + 4*NROWS;        // 32768 ints

    vq_cvt_kernel<<<(NROWS*64)/256, 256, 0, stream>>>(X, XsB);
    vq_cvt_kernel<<<(KCENT*64)/256, 256, 0, stream>>>(CB, CBsB);
    vq_cnorm_kernel<<<KCENT/4, 256, 0, stream>>>(CB, cnorm, out + O_CNT);
    vq_gemm_kernel<<<(NROWS/BM)*2, 512, 0, stream>>>(XsB, CBsB, cnorm, pmini4);
    vq_resolve_kernel<<<NROWS/4, 256, 0, stream>>>(X, CB, pmini4, fidx);
    vq_output_kernel<<<NROWS, 128, 0, stream>>>(X, CB, fidx, out);
    hipMemcpyAsync(out + O_CBV, CB, (size_t)KCENT * DDIM * sizeof(float),
                   hipMemcpyDeviceToDevice, stream);
}

// Round 4
// 1051.700 us; speedup vs baseline: 1.8978x; 1.2238x over previous
//
#include <hip/hip_runtime.h>

#define NROWS 32768
#define DDIM  512
#define KCENT 8192
#define BM 128
#define NCT 64              // centroid tiles of 128 cols
#define NSTEP (NCT*16)      // 16 K-chunks (BK=32) per tile

// out layout (floats): qout[16777216] loss[16777216] idx[32768] cbv[4194304] counts[8192]
#define O_LOSS 16777216
#define O_IDX  33554432
#define O_CBV  33587200
#define O_CNT  37781504

#define XT_BYTES 131072     // 128 rows * 1024 B (512 f16)
#define BB_BYTES 8192       // B chunk: 128 rows * 64 B (32 f16)

typedef float f32x4 __attribute__((ext_vector_type(4)));
typedef _Float16 f16x8 __attribute__((ext_vector_type(8)));

// ---- kernel 0a: fp32 -> f16, plain row-major (for X) ----
__global__ __launch_bounds__(256) void vq_cvt_plain(
    const float* __restrict__ src, char* __restrict__ dst)
{
    const size_t gid = (size_t)blockIdx.x * 256 + threadIdx.x;  // one 16B unit
    const float4* p = (const float4*)(src + gid * 8);
    float4 a = p[0], b = p[1];
    f16x8 h;
    h[0]=(_Float16)a.x; h[1]=(_Float16)a.y; h[2]=(_Float16)a.z; h[3]=(_Float16)a.w;
    h[4]=(_Float16)b.x; h[5]=(_Float16)b.y; h[6]=(_Float16)b.z; h[7]=(_Float16)b.w;
    *(f16x8*)(dst + gid * 16) = h;
}

// ---- kernel 0b: fp32 -> f16, 4-chunk swizzle within each 64B group (for CB) ----
// dst position (R, s, u) holds source chunk s*4 + (u ^ (R&3))
__global__ __launch_bounds__(256) void vq_cvt_swz4(
    const float* __restrict__ src, char* __restrict__ dst)
{
    const int gid = blockIdx.x * 256 + threadIdx.x;
    const int R = gid >> 6, w = gid & 63, s = w >> 2, u = w & 3;
    const int srcw = s * 4 + (u ^ (R & 3));
    const float4* p = (const float4*)(src + (size_t)R * DDIM + srcw * 8);
    float4 a = p[0], b = p[1];
    f16x8 h;
    h[0]=(_Float16)a.x; h[1]=(_Float16)a.y; h[2]=(_Float16)a.z; h[3]=(_Float16)a.w;
    h[4]=(_Float16)b.x; h[5]=(_Float16)b.y; h[6]=(_Float16)b.z; h[7]=(_Float16)b.w;
    *(f16x8*)(dst + (size_t)gid * 16) = h;
}

// ---- kernel 1: centroid squared norms (fp64 accumulate) + counts=1 ----
__global__ __launch_bounds__(256) void vq_cnorm_kernel(
    const float* __restrict__ CB, float* __restrict__ cnorm, float* __restrict__ counts)
{
    const int wid  = threadIdx.x >> 6;
    const int lane = threadIdx.x & 63;
    const int cid  = blockIdx.x * 4 + wid;
    const float4* p = (const float4*)(CB + (size_t)cid * DDIM + lane * 8);
    float4 a = p[0], b = p[1];
    double s = (double)a.x*a.x + (double)a.y*a.y + (double)a.z*a.z + (double)a.w*a.w
             + (double)b.x*b.x + (double)b.y*b.y + (double)b.z*b.z + (double)b.w*b.w;
    #pragma unroll
    for (int off = 32; off > 0; off >>= 1) s += __shfl_down(s, off);
    if (lane == 0) { cnorm[cid] = (float)s; counts[cid] = 1.0f; }
}

__device__ __forceinline__ void t2_update(float s, int c,
                                          float& v1, int& i1, float& v2, int& i2)
{
    if (s < v1)      { v2 = v1; i2 = i1; v1 = s; i1 = c; }
    else if (s < v2) { v2 = s;  i2 = c; }
}

__device__ __forceinline__ void t2_merge(float b1, int bi1, float b2, int bi2,
                                         float& a1, int& ai1, float& a2, int& ai2)
{
    if (b1 < a1 || (b1 == a1 && bi1 < ai1)) {
        float o1 = a1; int oi1 = ai1;
        a1 = b1; ai1 = bi1;
        if (b2 < o1 || (b2 == o1 && bi2 < oi1)) { a2 = b2; ai2 = bi2; }
        else                                    { a2 = o1; ai2 = oi1; }
    } else {
        if (b1 < a2 || (b1 == a2 && bi1 < ai2)) { a2 = b1; ai2 = bi1; }
    }
}

__device__ __forceinline__ void gl16(const char* g, const char* l)
{
    __builtin_amdgcn_global_load_lds(
        (const __attribute__((address_space(1))) void*)g,
        (__attribute__((address_space(3))) void*)l, 16, 0, 0);
}

// ---- kernel 2: f16 distance GEMM, X-tile LDS-resident, B dbuf, top-2 ----
__global__ __launch_bounds__(512, 2) void vq_gemm_kernel(
    const char* __restrict__ Xf, const char* __restrict__ Cf,
    const float* __restrict__ cnorm, int* __restrict__ pmini2)
{
    __shared__ __align__(16) char lds[XT_BYTES + 2*BB_BYTES];   // 144 KB

    const int bid  = blockIdx.x;
    const int rb   = bid * BM;
    const int t    = threadIdx.x;
    const int lane = t & 63;
    const int wid  = t >> 6;
    const int wr   = wid & 3;    // 4 row-groups of 32
    const int wc   = wid >> 2;   // 2 col-groups of 64
    const int l15  = lane & 15;
    const int lg   = lane >> 4;

    // ---- prologue: stage X tile (128 KB) via registers, 8-slot XOR swizzle ----
    // LDS position (r, p) holds data chunk p ^ (r&7)  [within each row's 64 chunks]
    #pragma unroll
    for (int i = 0; i < 16; ++i) {
        const int g = i*512 + t, r = g >> 6, w = g & 63;
        uint4 d = *(const uint4*)(Xf + (size_t)rb*1024 + (size_t)g*16);
        *(uint4*)(&lds[r*1024 + ((w ^ (r & 7)) * 16)]) = d;
    }
    // stage B chunk 0 (ct=0, dks=0)
    const int rB = t >> 2, uB = t & 3;
    gl16(Cf + (size_t)rB*1024 + uB*16, &lds[XT_BYTES + wid*1024]);
    __syncthreads();

    f32x4 acc[2][4];
    float rv1[2][4], rv2[2][4];
    int   ri1[2][4], ri2[2][4];
    #pragma unroll
    for (int m = 0; m < 2; ++m)
        #pragma unroll
        for (int n = 0; n < 4; ++n) {
            f32x4 z = {0.f,0.f,0.f,0.f};
            acc[m][n] = z;
            rv1[m][n] = 3.4e38f; rv2[m][n] = 3.4e38f;
            ri1[m][n] = 0x7fffffff; ri2[m][n] = 0x7fffffff;
        }

    int buf = 0;
    for (int ct = 0; ct < NCT; ++ct) {
        float cn[4];
        #pragma unroll
        for (int n = 0; n < 4; ++n) cn[n] = cnorm[ct*128 + wc*64 + n*16 + l15];

        for (int dks = 0; dks < 16; ++dks) {
            const int s = ct*16 + dks;
            if (s + 1 < NSTEP) {
                const int nct = (s+1) >> 4, ndks = (s+1) & 15;
                gl16(Cf + (size_t)(nct*128 + rB)*1024 + ndks*64 + uB*16,
                     &lds[XT_BYTES + (buf^1)*BB_BYTES + wid*1024]);
            }
            f16x8 A[2], B[4];
            #pragma unroll
            for (int m = 0; m < 2; ++m) {
                const int r = wr*32 + m*16 + l15;
                A[m] = *(const f16x8*)(&lds[r*1024 + (((dks*4 + lg) ^ (r & 7)) * 16)]);
            }
            #pragma unroll
            for (int n = 0; n < 4; ++n) {
                const int r = wc*64 + n*16 + l15;
                B[n] = *(const f16x8*)(&lds[XT_BYTES + buf*BB_BYTES + r*64 + ((lg ^ (r & 3)) * 16)]);
            }
            #pragma unroll
            for (int m = 0; m < 2; ++m)
                #pragma unroll
                for (int n = 0; n < 4; ++n)
                    acc[m][n] = __builtin_amdgcn_mfma_f32_16x16x32_f16(A[m], B[n], acc[m][n], 0, 0, 0);
            __syncthreads();
            buf ^= 1;
        }

        // per-tile epilogue: score = ||c||^2 - 2*dot ; running top-2 per row-slot
        #pragma unroll
        for (int n = 0; n < 4; ++n) {
            const int col = ct*128 + wc*64 + n*16 + l15;
            #pragma unroll
            for (int m = 0; m < 2; ++m) {
                #pragma unroll
                for (int j = 0; j < 4; ++j) {
                    const float sv = fmaf(-2.0f, acc[m][n][j], cn[n]);
                    t2_update(sv, col, rv1[m][j], ri1[m][j], rv2[m][j], ri2[m][j]);
                }
                f32x4 z = {0.f,0.f,0.f,0.f};
                acc[m][n] = z;
            }
        }
    }

    // cross-lane top-2 merge over the 16 l15 lanes (same row, different cols)
    #pragma unroll
    for (int m = 0; m < 2; ++m)
        #pragma unroll
        for (int j = 0; j < 4; ++j) {
            #pragma unroll
            for (int off = 1; off <= 8; off <<= 1) {
                float b1 = __shfl_xor(rv1[m][j], off);
                float b2 = __shfl_xor(rv2[m][j], off);
                int  bi1 = __shfl_xor(ri1[m][j], off);
                int  bi2 = __shfl_xor(ri2[m][j], off);
                t2_merge(b1, bi1, b2, bi2, rv1[m][j], ri1[m][j], rv2[m][j], ri2[m][j]);
            }
        }

    // cross-wave merge over the 2 col-groups via LDS (XT region reusable now)
    float* redv = (float*)&lds[0];      // [128][2][2]
    int*   redi = (int*)&lds[4096];     // [128][2][2]
    if (l15 == 0) {
        #pragma unroll
        for (int m = 0; m < 2; ++m)
            #pragma unroll
            for (int j = 0; j < 4; ++j) {
                const int rl = wr*32 + m*16 + lg*4 + j;
                redv[(rl*2 + wc)*2 + 0] = rv1[m][j];
                redv[(rl*2 + wc)*2 + 1] = rv2[m][j];
                redi[(rl*2 + wc)*2 + 0] = ri1[m][j];
                redi[(rl*2 + wc)*2 + 1] = ri2[m][j];
            }
    }
    __syncthreads();
    if (t < BM) {
        float a1 = redv[(t*2 + 0)*2 + 0], a2 = redv[(t*2 + 0)*2 + 1];
        int  ai1 = redi[(t*2 + 0)*2 + 0], ai2 = redi[(t*2 + 0)*2 + 1];
        t2_merge(redv[(t*2 + 1)*2 + 0], redi[(t*2 + 1)*2 + 0],
                 redv[(t*2 + 1)*2 + 1], redi[(t*2 + 1)*2 + 1],
                 a1, ai1, a2, ai2);
        const int row = rb + t;
        pmini2[row*2 + 0] = ai1;
        pmini2[row*2 + 1] = ai2;
    }
}

// ---- kernel 3: exact fp64 resolve of the 2 candidates + write all outputs ----
__global__ __launch_bounds__(256) void vq_resolve_out(
    const float* __restrict__ X, const float* __restrict__ CB,
    const int* __restrict__ pmini2, float* __restrict__ out)
{
    const int wid  = threadIdx.x >> 6;
    const int lane = threadIdx.x & 63;
    const int row  = blockIdx.x * 4 + wid;
    const int i0 = pmini2[row*2 + 0], i1 = pmini2[row*2 + 1];

    const float4* xp = (const float4*)(X + (size_t)row * DDIM + lane * 8);
    float4 xa = xp[0], xb = xp[1];
    const float4* p0 = (const float4*)(CB + (size_t)i0 * DDIM + lane * 8);
    float4 c0a = p0[0], c0b = p0[1];
    const float4* p1 = (const float4*)(CB + (size_t)i1 * DDIM + lane * 8);
    float4 c1a = p1[0], c1b = p1[1];

    double d0 = 0.0, d1 = 0.0, e;
    e = (double)xa.x - c0a.x; d0 += e*e;  e = (double)xa.y - c0a.y; d0 += e*e;
    e = (double)xa.z - c0a.z; d0 += e*e;  e = (double)xa.w - c0a.w; d0 += e*e;
    e = (double)xb.x - c0b.x; d0 += e*e;  e = (double)xb.y - c0b.y; d0 += e*e;
    e = (double)xb.z - c0b.z; d0 += e*e;  e = (double)xb.w - c0b.w; d0 += e*e;
    e = (double)xa.x - c1a.x; d1 += e*e;  e = (double)xa.y - c1a.y; d1 += e*e;
    e = (double)xa.z - c1a.z; d1 += e*e;  e = (double)xa.w - c1a.w; d1 += e*e;
    e = (double)xb.x - c1b.x; d1 += e*e;  e = (double)xb.y - c1b.y; d1 += e*e;
    e = (double)xb.z - c1b.z; d1 += e*e;  e = (double)xb.w - c1b.w; d1 += e*e;
    #pragma unroll
    for (int off = 1; off < 64; off <<= 1) {
        d0 += __shfl_xor(d0, off);
        d1 += __shfl_xor(d1, off);
    }

    const bool w1 = (d1 < d0) || (d1 == d0 && i1 < i0);
    const int idx = w1 ? i1 : i0;
    float4 qa, qb;
    qa.x = w1 ? c1a.x : c0a.x;  qa.y = w1 ? c1a.y : c0a.y;
    qa.z = w1 ? c1a.z : c0a.z;  qa.w = w1 ? c1a.w : c0a.w;
    qb.x = w1 ? c1b.x : c0b.x;  qb.y = w1 ? c1b.y : c0b.y;
    qb.z = w1 ? c1b.z : c0b.z;  qb.w = w1 ? c1b.w : c0b.w;

    float4 qoa, loa, qob, lob;
    float d, s;
    d = qa.x - xa.x; qoa.x = xa.x + d; s = d*d; loa.x = s + 0.25f*s;
    d = qa.y - xa.y; qoa.y = xa.y + d; s = d*d; loa.y = s + 0.25f*s;
    d = qa.z - xa.z; qoa.z = xa.z + d; s = d*d; loa.z = s + 0.25f*s;
    d = qa.w - xa.w; qoa.w = xa.w + d; s = d*d; loa.w = s + 0.25f*s;
    d = qb.x - xb.x; qob.x = xb.x + d; s = d*d; lob.x = s + 0.25f*s;
    d = qb.y - xb.y; qob.y = xb.y + d; s = d*d; lob.y = s + 0.25f*s;
    d = qb.z - xb.z; qob.z = xb.z + d; s = d*d; lob.z = s + 0.25f*s;
    d = qb.w - xb.w; qob.w = xb.w + d; s = d*d; lob.w = s + 0.25f*s;

    ((float4*)out)[(size_t)row*128 + lane*2 + 0] = qoa;
    ((float4*)out)[(size_t)row*128 + lane*2 + 1] = qob;
    ((float4*)(out + O_LOSS))[(size_t)row*128 + lane*2 + 0] = loa;
    ((float4*)(out + O_LOSS))[(size_t)row*128 + lane*2 + 1] = lob;
    if (lane == 0) out[O_IDX + row] = (float)idx;
}

extern "C" void kernel_launch(void* const* d_in, const int* in_sizes, int n_in,
                              void* d_out, int out_size, void* d_ws, size_t ws_size,
                              hipStream_t stream)
{
    const float* X  = (const float*)d_in[0];
    const float* CB = (const float*)d_in[1];
    float* out = (float*)d_out;

    // big f16 scratch lives in out regions (fully rewritten afterwards)
    char* XsB  = (char*)out;              // 32 MB plain f16 X     (qout region)
    char* CBsB = (char*)(out + O_LOSS);   //  8 MB swz4 f16 CB     (loss region)

    float* cnorm  = (float*)d_ws;             // 8192 floats
    int*   pmini2 = (int*)(cnorm + KCENT);    // 2*32768 ints

    vq_cvt_plain<<<(NROWS*64)/256, 256, 0, stream>>>(X, XsB);
    vq_cvt_swz4<<<(KCENT*64)/256, 256, 0, stream>>>(CB, CBsB);
    vq_cnorm_kernel<<<KCENT/4, 256, 0, stream>>>(CB, cnorm, out + O_CNT);
    vq_gemm_kernel<<<NROWS/BM, 512, 0, stream>>>(XsB, CBsB, cnorm, pmini2);
    vq_resolve_out<<<NROWS/4, 256, 0, stream>>>(X, CB, pmini2, out);
    hipMemcpyAsync(out + O_CBV, CB, (size_t)KCENT * DDIM * sizeof(float),
                   hipMemcpyDeviceToDevice, stream);
}